// Round 3
// baseline (515.078 us; speedup 1.0000x reference)
//
#include <hip/hip_runtime.h>
#include <hip/hip_bf16.h>

// EmbeddingBag mode='sum' — DIAGNOSTIC ROUND (REPS=8).
// The kernel's work is repeated 8x inside one dispatch (idempotent: each rep
// recomputes and overwrites identical bag sums, so correctness holds and every
// call does the same work). Purpose: push this dispatch above the harness's
// ~155us fill kernels so it appears in the rocprof top-5 WITH counters, and
// let dur_us reveal T_kernel via the slope (dur ~= fixed + 8*T).
// `zero` (runtime 0) is mixed into addressing so the compiler cannot hoist
// the gathers out of the rep loop.

#define EMB 64
#define REPS 8

__global__ __launch_bounds__(256) void embag_sum_kernel(
    const float* __restrict__ W,
    const int* __restrict__ indices,
    const int* __restrict__ offsets,
    float* __restrict__ out,
    int n_bags, int n_idx, int zero)
{
    const int wave = (int)((blockIdx.x * blockDim.x + threadIdx.x) >> 6);
    const int lane = (int)(threadIdx.x & 63);
    if (wave >= n_bags) return;

    const int slot = lane >> 4;    // row within 4-row group
    const int cg   = lane & 15;    // column group (float4)

    const int start = offsets[wave];
    const int end   = (wave + 1 < n_bags) ? offsets[wave + 1] : n_idx;

    for (int rep = 0; rep < REPS; ++rep) {
        const int roff = rep * zero;   // runtime 0, defeats LICM across reps

        float4 acc0 = {0.f,0.f,0.f,0.f}, acc1 = {0.f,0.f,0.f,0.f};
        float4 acc2 = {0.f,0.f,0.f,0.f}, acc3 = {0.f,0.f,0.f,0.f};

        for (int base = start; base < end; base += 64) {
            const int rem = end - base;
            const int cnt = rem < 64 ? rem : 64;
            const int myIdx = (lane < cnt) ? indices[base + lane + roff] : 0;

            for (int k = 0; k < cnt; k += 16) {
                const int r0 = k      + slot;
                const int r1 = k + 4  + slot;
                const int r2 = k + 8  + slot;
                const int r3 = k + 12 + slot;
                const unsigned i0 = (unsigned)__shfl(myIdx, r0, 64);
                const unsigned i1 = (unsigned)__shfl(myIdx, r1, 64);
                const unsigned i2 = (unsigned)__shfl(myIdx, r2, 64);
                const unsigned i3 = (unsigned)__shfl(myIdx, r3, 64);

                const float4 v0 = *(const float4*)(W + (size_t)i0 * EMB + cg * 4 + roff);
                const float4 v1 = *(const float4*)(W + (size_t)i1 * EMB + cg * 4 + roff);
                const float4 v2 = *(const float4*)(W + (size_t)i2 * EMB + cg * 4 + roff);
                const float4 v3 = *(const float4*)(W + (size_t)i3 * EMB + cg * 4 + roff);

                if (r0 < cnt) { acc0.x += v0.x; acc0.y += v0.y; acc0.z += v0.z; acc0.w += v0.w; }
                if (r1 < cnt) { acc1.x += v1.x; acc1.y += v1.y; acc1.z += v1.z; acc1.w += v1.w; }
                if (r2 < cnt) { acc2.x += v2.x; acc2.y += v2.y; acc2.z += v2.z; acc2.w += v2.w; }
                if (r3 < cnt) { acc3.x += v3.x; acc3.y += v3.y; acc3.z += v3.z; acc3.w += v3.w; }
            }
        }

        float4 acc;
        acc.x = (acc0.x + acc1.x) + (acc2.x + acc3.x);
        acc.y = (acc0.y + acc1.y) + (acc2.y + acc3.y);
        acc.z = (acc0.z + acc1.z) + (acc2.z + acc3.z);
        acc.w = (acc0.w + acc1.w) + (acc2.w + acc3.w);

        acc.x += __shfl_xor(acc.x, 16, 64);
        acc.y += __shfl_xor(acc.y, 16, 64);
        acc.z += __shfl_xor(acc.z, 16, 64);
        acc.w += __shfl_xor(acc.w, 16, 64);
        acc.x += __shfl_xor(acc.x, 32, 64);
        acc.y += __shfl_xor(acc.y, 32, 64);
        acc.z += __shfl_xor(acc.z, 32, 64);
        acc.w += __shfl_xor(acc.w, 32, 64);

        if (lane < 16) {
            *(float4*)(out + (size_t)wave * EMB + lane * 4 + roff) = acc;
        }
    }
}

extern "C" void kernel_launch(void* const* d_in, const int* in_sizes, int n_in,
                              void* d_out, int out_size, void* d_ws, size_t ws_size,
                              hipStream_t stream) {
    const float* W        = (const float*)d_in[0];
    const int*   indices  = (const int*)d_in[1];
    const int*   offsets  = (const int*)d_in[2];
    float*       out      = (float*)d_out;

    const int n_idx  = in_sizes[1];
    const int n_bags = in_sizes[2];

    const int waves_per_block = 256 / 64;
    const int n_blocks = (n_bags + waves_per_block - 1) / waves_per_block;

    embag_sum_kernel<<<n_blocks, 256, 0, stream>>>(W, indices, offsets, out,
                                                   n_bags, n_idx, /*zero=*/0);
}

// Round 4
// 324.080 us; speedup vs baseline: 1.5894x; 1.5894x over previous
//
#include <hip/hip_runtime.h>
#include <hip/hip_bf16.h>

// EmbeddingBag mode='sum':
//   W       : [1e6, 64] float32
//   indices : [819200] int32
//   offsets : [16384] int32 (bag starts; last bag ends at n_idx)
//   out     : [16384, 64] float32
//
// One wave per bag; 16 lanes per row x float4 => one global_load_dwordx4
// gathers 4 rows (1 KB). FULL UNROLL: all ceil(cnt/4) <= 16 row-group loads
// issued back-to-back (3.3 KB in flight per wave for 50-row bags, single
// vmcnt drain) to keep the CU's miss-tracking slots continuously full.
// Timing model (R3 diagnostic): headline dur_us = ~255us fixed harness
// restore/poison + kernel; kernel cold ~71us, limited by outstanding-miss
// capacity x HBM latency, not BW.

#define EMB 64

__global__ __launch_bounds__(256) void embag_sum_kernel(
    const float* __restrict__ W,
    const int* __restrict__ indices,
    const int* __restrict__ offsets,
    float* __restrict__ out,
    int n_bags, int n_idx)
{
    const int wave = (int)((blockIdx.x * blockDim.x + threadIdx.x) >> 6);
    const int lane = (int)(threadIdx.x & 63);
    if (wave >= n_bags) return;

    const int slot = lane >> 4;    // which row within a 4-row group
    const int cg   = lane & 15;    // which float4 column group

    const int start = offsets[wave];
    const int end   = (wave + 1 < n_bags) ? offsets[wave + 1] : n_idx;

    float4 a0 = {0.f,0.f,0.f,0.f};
    float4 a1 = {0.f,0.f,0.f,0.f};

    for (int base = start; base < end; base += 64) {
        const int rem = end - base;
        const int cnt = rem < 64 ? rem : 64;
        // one coalesced load of this chunk's indices; padded lanes -> row 0
        const int myIdx = (lane < cnt) ? indices[base + lane] : 0;
        const int ngroups = (cnt + 3) >> 2;   // <= 16, wave-uniform

#pragma unroll
        for (int g = 0; g < 16; ++g) {
            if (g < ngroups) {                 // wave-uniform guard
                const int r = g * 4 + slot;
                const unsigned i = (unsigned)__shfl(myIdx, r, 64);
                const float4 v = *(const float4*)(W + (size_t)i * EMB + cg * 4);
                const bool valid = (r < cnt);  // mask tail rows of last group
                if (g & 1) {
                    if (valid) { a1.x += v.x; a1.y += v.y; a1.z += v.z; a1.w += v.w; }
                } else {
                    if (valid) { a0.x += v.x; a0.y += v.y; a0.z += v.z; a0.w += v.w; }
                }
            }
        }
    }

    float4 acc;
    acc.x = a0.x + a1.x;
    acc.y = a0.y + a1.y;
    acc.z = a0.z + a1.z;
    acc.w = a0.w + a1.w;

    // reduce across the 4 row-slots (lane bits 4,5)
    acc.x += __shfl_xor(acc.x, 16, 64);
    acc.y += __shfl_xor(acc.y, 16, 64);
    acc.z += __shfl_xor(acc.z, 16, 64);
    acc.w += __shfl_xor(acc.w, 16, 64);
    acc.x += __shfl_xor(acc.x, 32, 64);
    acc.y += __shfl_xor(acc.y, 32, 64);
    acc.z += __shfl_xor(acc.z, 32, 64);
    acc.w += __shfl_xor(acc.w, 32, 64);

    if (lane < 16) {
        *(float4*)(out + (size_t)wave * EMB + lane * 4) = acc;
    }
}

extern "C" void kernel_launch(void* const* d_in, const int* in_sizes, int n_in,
                              void* d_out, int out_size, void* d_ws, size_t ws_size,
                              hipStream_t stream) {
    const float* W        = (const float*)d_in[0];
    const int*   indices  = (const int*)d_in[1];
    const int*   offsets  = (const int*)d_in[2];
    float*       out      = (float*)d_out;

    const int n_idx  = in_sizes[1];
    const int n_bags = in_sizes[2];

    const int waves_per_block = 256 / 64;
    const int n_blocks = (n_bags + waves_per_block - 1) / waves_per_block;

    embag_sum_kernel<<<n_blocks, 256, 0, stream>>>(W, indices, offsets, out,
                                                   n_bags, n_idx);
}

// Round 6
// 315.752 us; speedup vs baseline: 1.6313x; 1.0264x over previous
//
#include <hip/hip_runtime.h>
#include <hip/hip_bf16.h>

// EmbeddingBag mode='sum':
//   W       : [1e6, 64] float32
//   indices : [819200] int32
//   offsets : [16384] int32 (bag starts; last bag ends at n_idx)
//   out     : [16384, 64] float32
//
// One wave per bag; 16 lanes per row x float4 => one global_load_dwordx4
// gathers 4 rows (1 KB). Full unroll: all <=13 row-group loads issued
// back-to-back. R6 = R5 intent with compile fix: nontemporal load must go
// through a clang native ext_vector_type, not HIP_vector_type.
//
// Timing model (R3 diagnostic): headline = ~255us fixed harness
// restore/poison + kernel (~71us cold). Kernel is request-path-limited
// (~27 cyc/128B line/CU), invariant to issue shape (R1==R2==R4).

#define EMB 64

typedef float f32x4 __attribute__((ext_vector_type(4)));

__global__ __launch_bounds__(256) void embag_sum_kernel(
    const float* __restrict__ W,
    const int* __restrict__ indices,
    const int* __restrict__ offsets,
    float* __restrict__ out,
    int n_bags, int n_idx)
{
    const int wave = (int)((blockIdx.x * blockDim.x + threadIdx.x) >> 6);
    const int lane = (int)(threadIdx.x & 63);
    if (wave >= n_bags) return;

    const int slot = lane >> 4;    // which row within a 4-row group
    const int cg   = lane & 15;    // which float4 column group

    const int start = offsets[wave];
    const int end   = (wave + 1 < n_bags) ? offsets[wave + 1] : n_idx;

    f32x4 a0 = {0.f,0.f,0.f,0.f};
    f32x4 a1 = {0.f,0.f,0.f,0.f};

    for (int base = start; base < end; base += 64) {
        const int rem = end - base;
        const int cnt = rem < 64 ? rem : 64;
        // one coalesced load of this chunk's indices; padded lanes -> row 0
        const int myIdx = (lane < cnt) ? indices[base + lane] : 0;
        const int ngroups = (cnt + 3) >> 2;   // <= 16, wave-uniform

#pragma unroll
        for (int g = 0; g < 16; ++g) {
            if (g < ngroups) {                 // wave-uniform guard
                const int r = g * 4 + slot;
                const unsigned i = (unsigned)__shfl(myIdx, r, 64);
                const f32x4 v = __builtin_nontemporal_load(
                    (const f32x4*)(W + (size_t)i * EMB + cg * 4));
                const bool valid = (r < cnt);  // mask tail rows of last group
                if (g & 1) {
                    if (valid) a1 += v;
                } else {
                    if (valid) a0 += v;
                }
            }
        }
    }

    float accx = a0.x + a1.x;
    float accy = a0.y + a1.y;
    float accz = a0.z + a1.z;
    float accw = a0.w + a1.w;

    // reduce across the 4 row-slots (lane bits 4,5)
    accx += __shfl_xor(accx, 16, 64);
    accy += __shfl_xor(accy, 16, 64);
    accz += __shfl_xor(accz, 16, 64);
    accw += __shfl_xor(accw, 16, 64);
    accx += __shfl_xor(accx, 32, 64);
    accy += __shfl_xor(accy, 32, 64);
    accz += __shfl_xor(accz, 32, 64);
    accw += __shfl_xor(accw, 32, 64);

    if (lane < 16) {
        float4 o; o.x = accx; o.y = accy; o.z = accz; o.w = accw;
        *(float4*)(out + (size_t)wave * EMB + lane * 4) = o;
    }
}

extern "C" void kernel_launch(void* const* d_in, const int* in_sizes, int n_in,
                              void* d_out, int out_size, void* d_ws, size_t ws_size,
                              hipStream_t stream) {
    const float* W        = (const float*)d_in[0];
    const int*   indices  = (const int*)d_in[1];
    const int*   offsets  = (const int*)d_in[2];
    float*       out      = (float*)d_out;

    const int n_idx  = in_sizes[1];
    const int n_bags = in_sizes[2];

    const int waves_per_block = 256 / 64;
    const int n_blocks = (n_bags + waves_per_block - 1) / waves_per_block;

    embag_sum_kernel<<<n_blocks, 256, 0, stream>>>(W, indices, offsets, out,
                                                   n_bags, n_idx);
}